// Round 10
// baseline (180.771 us; speedup 1.0000x reference)
//
#include <hip/hip_runtime.h>
#include <hip/hip_bf16.h>

#define NB 4
#define SEQ 2048
#define NHEADS 8
#define ROWS (NB * SEQ)

typedef __attribute__((ext_vector_type(8))) short bf16x8;
typedef __attribute__((ext_vector_type(4))) short bf16x4;
typedef __attribute__((ext_vector_type(4))) float f32x4;
typedef __attribute__((ext_vector_type(16))) float f32x16;

__device__ inline short f2bf(float x) {
    union { float f; unsigned u; } v; v.f = x;
    unsigned r = v.u + 0x7FFF + ((v.u >> 16) & 1);
    return (short)(r >> 16);
}

__device__ inline unsigned pack2bf(float a, float b) {
    __hip_bfloat162 h = __float22bfloat162_rn(make_float2(a, b));
    unsigned u; __builtin_memcpy(&u, &h, 4);
    return u;
}

__device__ inline bf16x8 pack8(float4 a, float4 b) {
    union { unsigned u[4]; bf16x8 v; } r;
    r.u[0] = pack2bf(a.x, a.y);
    r.u[1] = pack2bf(a.z, a.w);
    r.u[2] = pack2bf(b.x, b.y);
    r.u[3] = pack2bf(b.z, b.w);
    return r.v;
}

// combine two packed-bf16 pairs from the two K-halves and scale: bf16 out
__device__ inline unsigned comb2(unsigned w1, unsigned w2, float inv) {
    union { unsigned v; float f; } a, b, c, d;
    a.v = w1 << 16;          b.v = w2 << 16;
    c.v = w1 & 0xffff0000u;  d.v = w2 & 0xffff0000u;
    return pack2bf((a.f + b.f) * inv, (c.f + d.f) * inv);
}

// ---------------------------------------------------------------------------
// fp32 -> bf16 cast for ctx only (x is consumed fp32 by the fused attn).
// ---------------------------------------------------------------------------
__global__ __launch_bounds__(256) void cvt_c(
    const float* __restrict__ ctx, short* __restrict__ cb)
{
    const int i = blockIdx.x * 256 + threadIdx.x;   // 524288 units of 4
    const float4 v = ((const float4*)ctx)[i];
    uint2 o2;
    o2.x = pack2bf(v.x, v.y);
    o2.y = pack2bf(v.z, v.w);
    *(uint2*)(cb + (size_t)i * 4) = o2;
}

// ---------------------------------------------------------------------------
// 128x128-tile bf16 MFMA GEMM (kv projection). CVT_W converts fp32 weights
// in-staging. XOR-swizzled unpadded LDS; register prefetch.
// ---------------------------------------------------------------------------
template <bool CVT_W>
__global__ __launch_bounds__(256) void gemm128(
    const short* __restrict__ A, const void* __restrict__ W_,
    const float* __restrict__ bias, short* __restrict__ out,
    int K, int Ccols, float scale)
{
    __shared__ short As[128 * 64];
    __shared__ short Ws[128 * 64];
    const int tid = threadIdx.x;
    const int w = tid >> 6, lane = tid & 63, low = lane & 15, quad = lane >> 4;
    const int wm = w >> 1, wn = w & 1;
    const int rM0 = blockIdx.y * 128, c0 = blockIdx.x * 128;
    const int srow = tid >> 3, sj = tid & 7;

    f32x4 acc[4][4];
#pragma unroll
    for (int mt = 0; mt < 4; ++mt)
#pragma unroll
        for (int nt = 0; nt < 4; ++nt) acc[mt][nt] = (f32x4){0.f, 0.f, 0.f, 0.f};

    float4 pwf[4][2];
    bf16x8 pab[4], pwb[4];

    auto loadA = [&](int c, int k0) {
        const int row = c * 32 + srow;
        pab[c] = *(const bf16x8*)(A + (size_t)(rM0 + row) * K + k0 + sj * 8);
    };
    auto loadW = [&](int c, int k0) {
        const int row = c * 32 + srow;
        if constexpr (CVT_W) {
            const float* p = (const float*)W_ + (size_t)(c0 + row) * K + k0 + sj * 8;
            pwf[c][0] = ((const float4*)p)[0];
            pwf[c][1] = ((const float4*)p)[1];
        } else {
            pwb[c] = *(const bf16x8*)((const short*)W_ + (size_t)(c0 + row) * K + k0 + sj * 8);
        }
    };

#pragma unroll
    for (int c = 0; c < 4; ++c) { loadA(c, 0); loadW(c, 0); }

    int k0 = 0;
    for (;;) {
        __syncthreads();
#pragma unroll
        for (int c = 0; c < 4; ++c) {
            const int row = c * 32 + srow;
            const int pc = sj ^ (row & 7);
            *(bf16x8*)(&As[row * 64 + pc * 8]) = pab[c];
            if constexpr (CVT_W) *(bf16x8*)(&Ws[row * 64 + pc * 8]) = pack8(pwf[c][0], pwf[c][1]);
            else                 *(bf16x8*)(&Ws[row * 64 + pc * 8]) = pwb[c];
        }
        __syncthreads();
        const int kn = k0 + 64;
        if (kn < K) {
#pragma unroll
            for (int c = 0; c < 4; ++c) { loadA(c, kn); loadW(c, kn); }
        }
#pragma unroll
        for (int kh = 0; kh < 2; ++kh) {
            bf16x8 af[4], bfv[4];
#pragma unroll
            for (int t = 0; t < 4; ++t) {
                const int ra = wm * 64 + t * 16 + low;
                af[t] = *(const bf16x8*)(&As[ra * 64 + ((kh * 4 + quad) ^ (ra & 7)) * 8]);
                const int rb = wn * 64 + t * 16 + low;
                bfv[t] = *(const bf16x8*)(&Ws[rb * 64 + ((kh * 4 + quad) ^ (rb & 7)) * 8]);
            }
#pragma unroll
            for (int mt = 0; mt < 4; ++mt)
#pragma unroll
                for (int nt = 0; nt < 4; ++nt)
                    acc[mt][nt] = __builtin_amdgcn_mfma_f32_16x16x32_bf16(af[mt], bfv[nt], acc[mt][nt], 0, 0, 0);
        }
        k0 = kn;
        if (k0 >= K) break;
    }

#pragma unroll
    for (int nt = 0; nt < 4; ++nt) {
        const int col = c0 + wn * 64 + nt * 16 + low;
        const float bv = bias[col];
#pragma unroll
        for (int mt = 0; mt < 4; ++mt) {
            const size_t rbase = (size_t)(rM0 + wm * 64 + mt * 16 + quad * 4);
#pragma unroll
            for (int r = 0; r < 4; ++r)
                out[(rbase + r) * Ccols + col] = f2bf((acc[mt][nt][r] + bv) * scale);
        }
    }
}

// ---------------------------------------------------------------------------
// o-GEMM with fused split-K combine: A[r][e] = (num1[r][e]+num2[r][e]) /
// (l1[r][h]+l2[r][h]) where h = e/64; BK=64 aligns with head boundary.
// ---------------------------------------------------------------------------
__global__ __launch_bounds__(256) void gemm64_ocomb(
    const short* __restrict__ num, const float* __restrict__ lbuf,
    const float* __restrict__ W, const float* __restrict__ bias,
    float* __restrict__ out)
{
    const int K = 512, Ccols = 256;
    const size_t NHALF = (size_t)ROWS * 512;
    const int R8 = ROWS * 8;
    __shared__ short As[64 * 64];
    __shared__ short Ws[64 * 64];
    const int tid = threadIdx.x;
    const int w = tid >> 6, lane = tid & 63, low = lane & 15, quad = lane >> 4;
    const int wm = w >> 1, wn = w & 1;
    const int r0 = blockIdx.y * 64, c0 = blockIdx.x * 64;
    const int srow = tid >> 2;
    const int sc = (tid & 3) * 2;

    f32x4 acc[2][2];
#pragma unroll
    for (int mt = 0; mt < 2; ++mt)
#pragma unroll
        for (int nt = 0; nt < 2; ++nt) acc[mt][nt] = (f32x4){0.f, 0.f, 0.f, 0.f};

    uint4 pa1[2], pa2[2];
    float pinv;
    float4 pwf[2][2];

    auto loadA = [&](int k0) {
        const int hh = k0 >> 6;
        const int row = r0 + srow;
        pinv = lbuf[row * 8 + hh] + lbuf[R8 + row * 8 + hh];
        const short* p1 = num + (size_t)row * 512 + k0 + sc * 8;
        pa1[0] = ((const uint4*)p1)[0];
        pa1[1] = ((const uint4*)p1)[1];
        const short* p2 = p1 + NHALF;
        pa2[0] = ((const uint4*)p2)[0];
        pa2[1] = ((const uint4*)p2)[1];
    };
    auto loadW = [&](int k0) {
        const float* p = W + (size_t)(c0 + srow) * K + k0 + sc * 8;
        pwf[0][0] = ((const float4*)p)[0]; pwf[0][1] = ((const float4*)p)[1];
        pwf[1][0] = ((const float4*)p)[2]; pwf[1][1] = ((const float4*)p)[3];
    };

    loadA(0); loadW(0);

    int k0 = 0;
    for (;;) {
        __syncthreads();
        {
            const float inv = 1.f / pinv;
#pragma unroll
            for (int c = 0; c < 2; ++c) {
                const int pc = (sc + c) ^ (srow & 7);
                union { unsigned u[4]; bf16x8 v; } r;
                r.u[0] = comb2(pa1[c].x, pa2[c].x, inv);
                r.u[1] = comb2(pa1[c].y, pa2[c].y, inv);
                r.u[2] = comb2(pa1[c].z, pa2[c].z, inv);
                r.u[3] = comb2(pa1[c].w, pa2[c].w, inv);
                *(bf16x8*)(&As[srow * 64 + pc * 8]) = r.v;
                *(bf16x8*)(&Ws[srow * 64 + pc * 8]) = pack8(pwf[c][0], pwf[c][1]);
            }
        }
        __syncthreads();
        const int kn = k0 + 64;
        if (kn < K) { loadA(kn); loadW(kn); }
#pragma unroll
        for (int kh = 0; kh < 2; ++kh) {
            bf16x8 af[2], bfv[2];
#pragma unroll
            for (int t = 0; t < 2; ++t) {
                const int ra = wm * 32 + t * 16 + low;
                af[t] = *(const bf16x8*)(&As[ra * 64 + ((kh * 4 + quad) ^ (ra & 7)) * 8]);
                const int rb = wn * 32 + t * 16 + low;
                bfv[t] = *(const bf16x8*)(&Ws[rb * 64 + ((kh * 4 + quad) ^ (rb & 7)) * 8]);
            }
#pragma unroll
            for (int mt = 0; mt < 2; ++mt)
#pragma unroll
                for (int nt = 0; nt < 2; ++nt)
                    acc[mt][nt] = __builtin_amdgcn_mfma_f32_16x16x32_bf16(af[mt], bfv[nt], acc[mt][nt], 0, 0, 0);
        }
        k0 = kn;
        if (k0 >= K) break;
    }

#pragma unroll
    for (int nt = 0; nt < 2; ++nt) {
        const int col = c0 + wn * 32 + nt * 16 + low;
        const float bv = bias[col];
#pragma unroll
        for (int mt = 0; mt < 2; ++mt) {
            const size_t rbase = (size_t)(r0 + wm * 32 + mt * 16 + quad * 4);
#pragma unroll
            for (int r = 0; r < 4; ++r)
                out[(rbase + r) * Ccols + col] = acc[mt][nt][r] + bv;
        }
    }
}

// ---------------------------------------------------------------------------
// MFMA flash attention (32x32x16) with FUSED Q-PROJECTION.
// Prologue: Qt = Wq_head(64x256) * x^T -> C col = query, row = dim; + bq,
//   * qscale; written to Qs[query][dim] (b64, same pattern as P stores);
//   read back as B-fragments qr[4] (b128). Removes the q-GEMM kernel and
//   the q2 workspace round trip.
// j-loop identical to R9 (split-K x2 over keys, XCD-swizzled 1-D grid).
// Layouts (32x32x16, verified m74/m101):
//   A: A[m = lane&31][k = (lane>>5)*8 + j]
//   B: B[k = (lane>>5)*8 + j][n = lane&31]
//   C: col(n) = lane&31, row(m) = (reg&3) + 8*(reg>>2) + 4*(lane>>5)
// ---------------------------------------------------------------------------
#define KST 72
#define VST 72
#define PST 72

__global__ __launch_bounds__(256) void attn_mfma(
    const float* __restrict__ x,    // ROWS x 256 fp32
    const float* __restrict__ Wq,   // 512 x 256 fp32
    const float* __restrict__ bq,   // 512 fp32
    const short* __restrict__ kv2,  // ROWS x 1024 bf16
    short* __restrict__ numb,       // 2 x ROWS x 512 bf16 (unnormalized O)
    float* __restrict__ lbuf)       // 2 x ROWS x 8 fp32
{
    __shared__ short Ks[64 * KST];     // j-loop K tile; prologue: wqs
    __shared__ short Vt[64 * VST];     // j-loop V^T tile
    __shared__ short Ps[4][32 * PST];  // j-loop P; prologue: xs (128x72) then Qs

    const int tid = threadIdx.x;
    const int w = tid >> 6;
    const int lane = tid & 63;
    const int l31 = lane & 31;
    const int h2 = lane >> 5;

    // XCD swizzle decode
    const int flat = blockIdx.x;
    const int h = flat & 7;
    const int rest = flat >> 3;
    const int half = rest & 1;
    const int rest2 = rest >> 1;
    const int qtile = rest2 & 15;
    const int b = rest2 >> 4;
    const int iq0 = qtile * 128;
    const int jt0 = half * 16;

    const float qscale = 0.125f * 1.44269504088896f;   // softmax scale + log2e

    // ===== fused Q projection: Qt = Wq_head * x^T (+bq, *qscale) =====
    bf16x8 qr[4];
    {
        short* xs = &Ps[0][0];         // 128 x PST
        short* wqs = Ks;               // 64 x KST
        f32x16 qacc[2];
#pragma unroll
        for (int dg = 0; dg < 2; ++dg)
#pragma unroll
            for (int r = 0; r < 16; ++r) qacc[dg][r] = 0.f;

        const int xrow = tid >> 1;           // 0..127
        const int xkc = (tid & 1) * 32;      // 0 / 32
        const int wrow = tid >> 2;           // 0..63
        const int wkc = (tid & 3) * 16;      // 0..48

        for (int k0 = 0; k0 < 256; k0 += 64) {
            __syncthreads();
            {
                const float* xp = x + (size_t)(b * SEQ + iq0 + xrow) * 256 + k0 + xkc;
                *(bf16x8*)(&xs[xrow * PST + xkc])      = pack8(((const float4*)xp)[0], ((const float4*)xp)[1]);
                *(bf16x8*)(&xs[xrow * PST + xkc + 8])  = pack8(((const float4*)xp)[2], ((const float4*)xp)[3]);
                *(bf16x8*)(&xs[xrow * PST + xkc + 16]) = pack8(((const float4*)xp)[4], ((const float4*)xp)[5]);
                *(bf16x8*)(&xs[xrow * PST + xkc + 24]) = pack8(((const float4*)xp)[6], ((const float4*)xp)[7]);
                const float* wp = Wq + (size_t)(h * 64 + wrow) * 256 + k0 + wkc;
                *(bf16x8*)(&wqs[wrow * KST + wkc])     = pack8(((const float4*)wp)[0], ((const float4*)wp)[1]);
                *(bf16x8*)(&wqs[wrow * KST + wkc + 8]) = pack8(((const float4*)wp)[2], ((const float4*)wp)[3]);
            }
            __syncthreads();
#pragma unroll
            for (int st = 0; st < 4; ++st) {
                const bf16x8 bx = *(const bf16x8*)(&xs[(w * 32 + l31) * PST + st * 16 + h2 * 8]);
#pragma unroll
                for (int dg = 0; dg < 2; ++dg) {
                    const bf16x8 aw = *(const bf16x8*)(&wqs[(dg * 32 + l31) * KST + st * 16 + h2 * 8]);
                    qacc[dg] = __builtin_amdgcn_mfma_f32_32x32x16_bf16(aw, bx, qacc[dg], 0, 0, 0);
                }
            }
        }
        __syncthreads();   // xs/wqs dead; Ps area becomes Qs
        short* Qs = &Ps[w][0];   // 32 x PST, per-wave
#pragma unroll
        for (int dg = 0; dg < 2; ++dg)
#pragma unroll
            for (int g = 0; g < 4; ++g) {
                const int d0 = dg * 32 + 8 * g + 4 * h2;
                const float v0 = (qacc[dg][4 * g + 0] + bq[h * 64 + d0 + 0]) * qscale;
                const float v1 = (qacc[dg][4 * g + 1] + bq[h * 64 + d0 + 1]) * qscale;
                const float v2 = (qacc[dg][4 * g + 2] + bq[h * 64 + d0 + 2]) * qscale;
                const float v3 = (qacc[dg][4 * g + 3] + bq[h * 64 + d0 + 3]) * qscale;
                uint2 u;
                u.x = pack2bf(v0, v1);
                u.y = pack2bf(v2, v3);
                *(uint2*)(&Qs[l31 * PST + d0]) = u;
            }
        __builtin_amdgcn_wave_barrier();
#pragma unroll
        for (int st = 0; st < 4; ++st)
            qr[st] = *(const bf16x8*)(&Qs[l31 * PST + st * 16 + h2 * 8]);
    }

    const short* kbase = kv2 + (size_t)(b * SEQ) * 1024 + h * 64;
    const short* vbase = kbase + 512;
    short* pw = &Ps[w][0];

    float lsum = 0.f;                 // partial: query = l31, this lane's keys
    f32x16 oacc[2];                   // [dg]; col = dim, rows = queries
#pragma unroll
    for (int dg = 0; dg < 2; ++dg)
#pragma unroll
        for (int r = 0; r < 16; ++r) oacc[dg][r] = 0.f;

    // staging indices
    const int krow = tid >> 2;          // key row 0..63
    const int kc = (tid & 3) * 16;      // dim chunk (shorts)
    const int vk4 = (tid & 15) * 4;     // key base (V^T)
    const int vd4 = (tid >> 4) * 4;     // dim base 0..60

    // --- prefetch first tile of this half ---
    bf16x8 pk0, pk1;
    bf16x4 pv0, pv1, pv2, pv3;
    {
        const short* ksrc = kbase + (size_t)(jt0 * 64 + krow) * 1024 + kc;
        pk0 = *(const bf16x8*)(ksrc);
        pk1 = *(const bf16x8*)(ksrc + 8);
        const short* vs = vbase + (size_t)(jt0 * 64 + vk4) * 1024 + vd4;
        pv0 = *(const bf16x4*)(vs);
        pv1 = *(const bf16x4*)(vs + 1024);
        pv2 = *(const bf16x4*)(vs + 2048);
        pv3 = *(const bf16x4*)(vs + 3072);
    }

    for (int jt = jt0; jt < jt0 + 16; ++jt) {
        __syncthreads();
        *(bf16x8*)(&Ks[krow * KST + kc]) = pk0;
        *(bf16x8*)(&Ks[krow * KST + kc + 8]) = pk1;
        {
            bf16x4 c0_, c1_, c2_, c3_;
            c0_[0] = pv0[0]; c0_[1] = pv1[0]; c0_[2] = pv2[0]; c0_[3] = pv3[0];
            c1_[0] = pv0[1]; c1_[1] = pv1[1]; c1_[2] = pv2[1]; c1_[3] = pv3[1];
            c2_[0] = pv0[2]; c2_[1] = pv1[2]; c2_[2] = pv2[2]; c2_[3] = pv3[2];
            c3_[0] = pv0[3]; c3_[1] = pv1[3]; c3_[2] = pv2[3]; c3_[3] = pv3[3];
            *(bf16x4*)(&Vt[(vd4 + 0) * VST + vk4]) = c0_;
            *(bf16x4*)(&Vt[(vd4 + 1) * VST + vk4]) = c1_;
            *(bf16x4*)(&Vt[(vd4 + 2) * VST + vk4]) = c2_;
            *(bf16x4*)(&Vt[(vd4 + 3) * VST + vk4]) = c3_;
        }
        __syncthreads();

        // prefetch next tile
        if (jt + 1 < jt0 + 16) {
            const short* ksrc = kbase + (size_t)((jt + 1) * 64 + krow) * 1024 + kc;
            pk0 = *(const bf16x8*)(ksrc);
            pk1 = *(const bf16x8*)(ksrc + 8);
            const short* vs = vbase + (size_t)((jt + 1) * 64 + vk4) * 1024 + vd4;
            pv0 = *(const bf16x4*)(vs);
            pv1 = *(const bf16x4*)(vs + 1024);
            pv2 = *(const bf16x4*)(vs + 2048);
            pv3 = *(const bf16x4*)(vs + 3072);
        }

        // --- S^T = K Q^T (2 key-groups x 4 k-steps), P = exp2, b64 stores ---
#pragma unroll
        for (int kg = 0; kg < 2; ++kg) {
            f32x16 s;
#pragma unroll
            for (int r = 0; r < 16; ++r) s[r] = 0.f;
#pragma unroll
            for (int st = 0; st < 4; ++st) {
                const bf16x8 kf = *(const bf16x8*)(&Ks[(kg * 32 + l31) * KST + st * 16 + h2 * 8]);
                s = __builtin_amdgcn_mfma_f32_32x32x16_bf16(kf, qr[st], s, 0, 0, 0);
            }
#pragma unroll
            for (int g = 0; g < 4; ++g) {
                const float p0 = __builtin_amdgcn_exp2f(s[4 * g + 0]);
                const float p1 = __builtin_amdgcn_exp2f(s[4 * g + 1]);
                const float p2 = __builtin_amdgcn_exp2f(s[4 * g + 2]);
                const float p3 = __builtin_amdgcn_exp2f(s[4 * g + 3]);
                lsum += (p0 + p1) + (p2 + p3);
                uint2 u;
                u.x = pack2bf(p0, p1);
                u.y = pack2bf(p2, p3);
                *(uint2*)(&pw[l31 * PST + kg * 32 + 8 * g + 4 * h2]) = u;
            }
        }
        __builtin_amdgcn_wave_barrier();

        // --- O += P V (4 k-steps x 2 dim-groups) ---
#pragma unroll
        for (int st = 0; st < 4; ++st) {
            const bf16x8 pf = *(const bf16x8*)(&pw[l31 * PST + st * 16 + h2 * 8]);
#pragma unroll
            for (int dg = 0; dg < 2; ++dg) {
                const bf16x8 vf = *(const bf16x8*)(&Vt[(dg * 32 + l31) * VST + st * 16 + h2 * 8]);
                oacc[dg] = __builtin_amdgcn_mfma_f32_32x32x16_bf16(pf, vf, oacc[dg], 0, 0, 0);
            }
        }
        __builtin_amdgcn_wave_barrier();
    }

    // --- epilogue: combine h2 halves of lsum; store partial l and O ---
    lsum += __shfl_xor(lsum, 32);     // all 64 keys for query = w*32 + l31
    short* nb = numb + (size_t)half * ROWS * 512;
    float* lb = lbuf + (size_t)half * ROWS * 8;
    if (lane < 32)
        lb[(size_t)(b * SEQ + iq0 + w * 32 + l31) * 8 + h] = lsum;
#pragma unroll
    for (int dg = 0; dg < 2; ++dg)
#pragma unroll
        for (int r = 0; r < 16; ++r) {
            const int qrow = w * 32 + (r & 3) + 8 * (r >> 2) + 4 * h2;
            nb[(size_t)(b * SEQ + iq0 + qrow) * 512 + h * 64 + dg * 32 + l31] =
                f2bf(oacc[dg][r]);
        }
}

// ---------------------------------------------------------------------------
extern "C" void kernel_launch(void* const* d_in, const int* in_sizes, int n_in,
                              void* d_out, int out_size, void* d_ws, size_t ws_size,
                              hipStream_t stream) {
    const float* x   = (const float*)d_in[0];  // (4,2048,256)
    const float* ctx = (const float*)d_in[1];  // (4,2048,256)
    const float* Wq  = (const float*)d_in[2];  // (512,256)
    const float* bq  = (const float*)d_in[3];
    const float* Wkv = (const float*)d_in[4];  // (1024,256)
    const float* bkv = (const float*)d_in[5];
    const float* Wo  = (const float*)d_in[6];  // (256,512)
    const float* bo  = (const float*)d_in[7];
    float* out = (float*)d_out;                // (4,2048,256) fp32

    short* cb   = (short*)d_ws;                         // ROWS*256
    short* kv2b = cb + (size_t)ROWS * 256;              // ROWS*1024
    short* numb = kv2b + (size_t)ROWS * 1024;           // 2*ROWS*512
    float* lbuf = (float*)(numb + (size_t)2 * ROWS * 512); // 2*ROWS*8

    cvt_c<<<2048, 256, 0, stream>>>(ctx, cb);

    // kv = ctx*Wkv^T + bkv
    gemm128<true><<<dim3(1024 / 128, ROWS / 128), 256, 0, stream>>>(
        cb, Wkv, bkv, kv2b, 256, 1024, 1.0f);
    // attention with fused q-projection, split-K x2, XCD-swizzled (1024 blocks)
    attn_mfma<<<NB * NHEADS * (SEQ / 128) * 2, 256, 0, stream>>>(
        x, Wq, bq, kv2b, numb, lbuf);
    // out = combine(num1,num2)/(l1+l2) * Wo^T + bo
    gemm64_ocomb<<<dim3(256 / 64, ROWS / 64), 256, 0, stream>>>(
        numb, lbuf, Wo, bo, out);
}

// Round 11
// 172.233 us; speedup vs baseline: 1.0496x; 1.0496x over previous
//
#include <hip/hip_runtime.h>
#include <hip/hip_bf16.h>

#define NB 4
#define SEQ 2048
#define NHEADS 8
#define ROWS (NB * SEQ)

typedef __attribute__((ext_vector_type(8))) short bf16x8;
typedef __attribute__((ext_vector_type(4))) short bf16x4;
typedef __attribute__((ext_vector_type(4))) float f32x4;
typedef __attribute__((ext_vector_type(16))) float f32x16;

__device__ inline short f2bf(float x) {
    union { float f; unsigned u; } v; v.f = x;
    unsigned r = v.u + 0x7FFF + ((v.u >> 16) & 1);
    return (short)(r >> 16);
}

__device__ inline unsigned pack2bf(float a, float b) {
    __hip_bfloat162 h = __float22bfloat162_rn(make_float2(a, b));
    unsigned u; __builtin_memcpy(&u, &h, 4);
    return u;
}

__device__ inline bf16x8 pack8(float4 a, float4 b) {
    union { unsigned u[4]; bf16x8 v; } r;
    r.u[0] = pack2bf(a.x, a.y);
    r.u[1] = pack2bf(a.z, a.w);
    r.u[2] = pack2bf(b.x, b.y);
    r.u[3] = pack2bf(b.z, b.w);
    return r.v;
}

// combine two packed-bf16 pairs from the two K-halves and scale: bf16 out
__device__ inline unsigned comb2(unsigned w1, unsigned w2, float inv) {
    union { unsigned v; float f; } a, b, c, d;
    a.v = w1 << 16;          b.v = w2 << 16;
    c.v = w1 & 0xffff0000u;  d.v = w2 & 0xffff0000u;
    return pack2bf((a.f + b.f) * inv, (c.f + d.f) * inv);
}

// ---------------------------------------------------------------------------
// Fused projection kernel: q = x*Wq^T+bq (scaled) AND kv = ctx*Wkv^T+bkv.
// One launch, 3072 blocks, uniform 64x64-tile path, K=256, fp32 A/W converted
// to bf16 in-staging. Block specialization:
//   bid <  1024 : q tiles  — unit u = col*128 + row (8 cols x 128 rows)
//   bid >= 1024 : kv tiles — unit u = col*128 + row (16 cols x 128 rows)
// Column-major unit order: the readers of one A row-strip are 128 blocks
// apart -> same XCD -> fp32 A fetched once per strip (L2-resident re-reads).
// XOR-swizzled unpadded LDS; register prefetch across K-iters.
// ---------------------------------------------------------------------------
__global__ __launch_bounds__(256) void proj(
    const float* __restrict__ x, const float* __restrict__ Wq,
    const float* __restrict__ bq, const float* __restrict__ ctx,
    const float* __restrict__ Wkv, const float* __restrict__ bkv,
    short* __restrict__ q2b, short* __restrict__ kv2b, float qscale)
{
    __shared__ short As[64 * 64];
    __shared__ short Ws[64 * 64];
    const int tid = threadIdx.x;
    const int bid = blockIdx.x;
    const int w = tid >> 6, lane = tid & 63, low = lane & 15, quad = lane >> 4;
    const int wm = w >> 1, wn = w & 1;
    const int K = 256;

    const float* A; const float* W; const float* bias;
    short* outp; int Ccols; float scale; int u;
    if (bid < 1024) {
        u = bid; A = x; W = Wq; bias = bq; outp = q2b;
        Ccols = 512; scale = qscale;
    } else {
        u = bid - 1024; A = ctx; W = Wkv; bias = bkv; outp = kv2b;
        Ccols = 1024; scale = 1.0f;
    }
    const int c0 = (u >> 7) * 64;
    const int r0 = (u & 127) * 64;

    const int srow = tid >> 2;          // 0..63
    const int sc = (tid & 3) * 2;       // chunk pair {0,2,4,6}

    f32x4 acc[2][2];
#pragma unroll
    for (int mt = 0; mt < 2; ++mt)
#pragma unroll
        for (int nt = 0; nt < 2; ++nt) acc[mt][nt] = (f32x4){0.f, 0.f, 0.f, 0.f};

    float4 paf[2][2], pwf[2][2];
    auto loadA = [&](int k0) {
        const float* p = A + (size_t)(r0 + srow) * K + k0 + sc * 8;
        paf[0][0] = ((const float4*)p)[0]; paf[0][1] = ((const float4*)p)[1];
        paf[1][0] = ((const float4*)p)[2]; paf[1][1] = ((const float4*)p)[3];
    };
    auto loadW = [&](int k0) {
        const float* p = W + (size_t)(c0 + srow) * K + k0 + sc * 8;
        pwf[0][0] = ((const float4*)p)[0]; pwf[0][1] = ((const float4*)p)[1];
        pwf[1][0] = ((const float4*)p)[2]; pwf[1][1] = ((const float4*)p)[3];
    };

    loadA(0); loadW(0);

    int k0 = 0;
    for (;;) {
        __syncthreads();
#pragma unroll
        for (int c = 0; c < 2; ++c) {
            const int pc = (sc + c) ^ (srow & 7);
            *(bf16x8*)(&As[srow * 64 + pc * 8]) = pack8(paf[c][0], paf[c][1]);
            *(bf16x8*)(&Ws[srow * 64 + pc * 8]) = pack8(pwf[c][0], pwf[c][1]);
        }
        __syncthreads();
        const int kn = k0 + 64;
        if (kn < K) { loadA(kn); loadW(kn); }
#pragma unroll
        for (int kh = 0; kh < 2; ++kh) {
            bf16x8 af[2], bfv[2];
#pragma unroll
            for (int t = 0; t < 2; ++t) {
                const int ra = wm * 32 + t * 16 + low;
                af[t] = *(const bf16x8*)(&As[ra * 64 + ((kh * 4 + quad) ^ (ra & 7)) * 8]);
                const int rb = wn * 32 + t * 16 + low;
                bfv[t] = *(const bf16x8*)(&Ws[rb * 64 + ((kh * 4 + quad) ^ (rb & 7)) * 8]);
            }
#pragma unroll
            for (int mt = 0; mt < 2; ++mt)
#pragma unroll
                for (int nt = 0; nt < 2; ++nt)
                    acc[mt][nt] = __builtin_amdgcn_mfma_f32_16x16x32_bf16(af[mt], bfv[nt], acc[mt][nt], 0, 0, 0);
        }
        k0 = kn;
        if (k0 >= K) break;
    }

#pragma unroll
    for (int nt = 0; nt < 2; ++nt) {
        const int col = c0 + wn * 32 + nt * 16 + low;
        const float bv = bias[col];
#pragma unroll
        for (int mt = 0; mt < 2; ++mt) {
            const size_t rbase = (size_t)(r0 + wm * 32 + mt * 16 + quad * 4);
#pragma unroll
            for (int r = 0; r < 4; ++r)
                outp[(rbase + r) * Ccols + col] = f2bf((acc[mt][nt][r] + bv) * scale);
        }
    }
}

// ---------------------------------------------------------------------------
// o-GEMM with fused split-K combine: A[r][e] = (num1[r][e]+num2[r][e]) /
// (l1[r][h]+l2[r][h]) where h = e/64; BK=64 aligns with head boundary.
// ---------------------------------------------------------------------------
__global__ __launch_bounds__(256) void gemm64_ocomb(
    const short* __restrict__ num, const float* __restrict__ lbuf,
    const float* __restrict__ W, const float* __restrict__ bias,
    float* __restrict__ out)
{
    const int K = 512, Ccols = 256;
    const size_t NHALF = (size_t)ROWS * 512;
    const int R8 = ROWS * 8;
    __shared__ short As[64 * 64];
    __shared__ short Ws[64 * 64];
    const int tid = threadIdx.x;
    const int w = tid >> 6, lane = tid & 63, low = lane & 15, quad = lane >> 4;
    const int wm = w >> 1, wn = w & 1;
    const int r0 = blockIdx.y * 64, c0 = blockIdx.x * 64;
    const int srow = tid >> 2;
    const int sc = (tid & 3) * 2;

    f32x4 acc[2][2];
#pragma unroll
    for (int mt = 0; mt < 2; ++mt)
#pragma unroll
        for (int nt = 0; nt < 2; ++nt) acc[mt][nt] = (f32x4){0.f, 0.f, 0.f, 0.f};

    uint4 pa1[2], pa2[2];
    float pinv;
    float4 pwf[2][2];

    auto loadA = [&](int k0) {
        const int hh = k0 >> 6;
        const int row = r0 + srow;
        pinv = lbuf[row * 8 + hh] + lbuf[R8 + row * 8 + hh];
        const short* p1 = num + (size_t)row * 512 + k0 + sc * 8;
        pa1[0] = ((const uint4*)p1)[0];
        pa1[1] = ((const uint4*)p1)[1];
        const short* p2 = p1 + NHALF;
        pa2[0] = ((const uint4*)p2)[0];
        pa2[1] = ((const uint4*)p2)[1];
    };
    auto loadW = [&](int k0) {
        const float* p = W + (size_t)(c0 + srow) * K + k0 + sc * 8;
        pwf[0][0] = ((const float4*)p)[0]; pwf[0][1] = ((const float4*)p)[1];
        pwf[1][0] = ((const float4*)p)[2]; pwf[1][1] = ((const float4*)p)[3];
    };

    loadA(0); loadW(0);

    int k0 = 0;
    for (;;) {
        __syncthreads();
        {
            const float inv = 1.f / pinv;
#pragma unroll
            for (int c = 0; c < 2; ++c) {
                const int pc = (sc + c) ^ (srow & 7);
                union { unsigned u[4]; bf16x8 v; } r;
                r.u[0] = comb2(pa1[c].x, pa2[c].x, inv);
                r.u[1] = comb2(pa1[c].y, pa2[c].y, inv);
                r.u[2] = comb2(pa1[c].z, pa2[c].z, inv);
                r.u[3] = comb2(pa1[c].w, pa2[c].w, inv);
                *(bf16x8*)(&As[srow * 64 + pc * 8]) = r.v;
                *(bf16x8*)(&Ws[srow * 64 + pc * 8]) = pack8(pwf[c][0], pwf[c][1]);
            }
        }
        __syncthreads();
        const int kn = k0 + 64;
        if (kn < K) { loadA(kn); loadW(kn); }
#pragma unroll
        for (int kh = 0; kh < 2; ++kh) {
            bf16x8 af[2], bfv[2];
#pragma unroll
            for (int t = 0; t < 2; ++t) {
                const int ra = wm * 32 + t * 16 + low;
                af[t] = *(const bf16x8*)(&As[ra * 64 + ((kh * 4 + quad) ^ (ra & 7)) * 8]);
                const int rb = wn * 32 + t * 16 + low;
                bfv[t] = *(const bf16x8*)(&Ws[rb * 64 + ((kh * 4 + quad) ^ (rb & 7)) * 8]);
            }
#pragma unroll
            for (int mt = 0; mt < 2; ++mt)
#pragma unroll
                for (int nt = 0; nt < 2; ++nt)
                    acc[mt][nt] = __builtin_amdgcn_mfma_f32_16x16x32_bf16(af[mt], bfv[nt], acc[mt][nt], 0, 0, 0);
        }
        k0 = kn;
        if (k0 >= K) break;
    }

#pragma unroll
    for (int nt = 0; nt < 2; ++nt) {
        const int col = c0 + wn * 32 + nt * 16 + low;
        const float bv = bias[col];
#pragma unroll
        for (int mt = 0; mt < 2; ++mt) {
            const size_t rbase = (size_t)(r0 + wm * 32 + mt * 16 + quad * 4);
#pragma unroll
            for (int r = 0; r < 4; ++r)
                out[(rbase + r) * Ccols + col] = acc[mt][nt][r] + bv;
        }
    }
}

// ---------------------------------------------------------------------------
// MFMA flash attention (32x32x16), R9 structure: split-K x2 over keys,
// XCD-swizzled 1-D grid, reads pre-projected/pre-scaled q2.
// Layouts (32x32x16, verified m74/m101):
//   A: A[m = lane&31][k = (lane>>5)*8 + j]
//   B: B[k = (lane>>5)*8 + j][n = lane&31]
//   C: col(n) = lane&31, row(m) = (reg&3) + 8*(reg>>2) + 4*(lane>>5)
// S^T = K Q^T -> C col = query; lsum scalar per lane; P b64 stores.
// O = P V -> C col = dim, rows = queries; unnormalized stores (split-K).
// ---------------------------------------------------------------------------
#define KST 72
#define VST 72
#define PST 72

__global__ __launch_bounds__(256) void attn_mfma(
    const short* __restrict__ q2,   // ROWS x 512 bf16 (pre-scaled)
    const short* __restrict__ kv2,  // ROWS x 1024 bf16
    short* __restrict__ numb,       // 2 x ROWS x 512 bf16 (unnormalized O)
    float* __restrict__ lbuf)       // 2 x ROWS x 8 fp32
{
    __shared__ short Ks[64 * KST];
    __shared__ short Vt[64 * VST];
    __shared__ short Ps[4][32 * PST];

    const int tid = threadIdx.x;
    const int w = tid >> 6;
    const int lane = tid & 63;
    const int l31 = lane & 31;
    const int h2 = lane >> 5;

    // XCD swizzle decode
    const int flat = blockIdx.x;
    const int h = flat & 7;
    const int rest = flat >> 3;
    const int half = rest & 1;
    const int rest2 = rest >> 1;
    const int qtile = rest2 & 15;
    const int b = rest2 >> 4;
    const int iq0 = qtile * 128;
    const int jt0 = half * 16;

    // --- Q fragments: B operand, 4 k-steps, registers all kernel ---
    bf16x8 qr[4];
#pragma unroll
    for (int st = 0; st < 4; ++st)
        qr[st] = *(const bf16x8*)(q2 + (size_t)(b * SEQ + iq0 + w * 32 + l31) * 512
                                  + h * 64 + st * 16 + h2 * 8);

    const short* kbase = kv2 + (size_t)(b * SEQ) * 1024 + h * 64;
    const short* vbase = kbase + 512;
    short* pw = &Ps[w][0];

    float lsum = 0.f;                 // partial: query = l31, this lane's keys
    f32x16 oacc[2];                   // [dg]; col = dim, rows = queries
#pragma unroll
    for (int dg = 0; dg < 2; ++dg)
#pragma unroll
        for (int r = 0; r < 16; ++r) oacc[dg][r] = 0.f;

    // staging indices
    const int krow = tid >> 2;          // key row 0..63
    const int kc = (tid & 3) * 16;      // dim chunk (shorts)
    const int vk4 = (tid & 15) * 4;     // key base (V^T)
    const int vd4 = (tid >> 4) * 4;     // dim base 0..60

    // --- prefetch first tile of this half ---
    bf16x8 pk0, pk1;
    bf16x4 pv0, pv1, pv2, pv3;
    {
        const short* ksrc = kbase + (size_t)(jt0 * 64 + krow) * 1024 + kc;
        pk0 = *(const bf16x8*)(ksrc);
        pk1 = *(const bf16x8*)(ksrc + 8);
        const short* vs = vbase + (size_t)(jt0 * 64 + vk4) * 1024 + vd4;
        pv0 = *(const bf16x4*)(vs);
        pv1 = *(const bf16x4*)(vs + 1024);
        pv2 = *(const bf16x4*)(vs + 2048);
        pv3 = *(const bf16x4*)(vs + 3072);
    }

    for (int jt = jt0; jt < jt0 + 16; ++jt) {
        __syncthreads();
        *(bf16x8*)(&Ks[krow * KST + kc]) = pk0;
        *(bf16x8*)(&Ks[krow * KST + kc + 8]) = pk1;
        {
            bf16x4 c0_, c1_, c2_, c3_;
            c0_[0] = pv0[0]; c0_[1] = pv1[0]; c0_[2] = pv2[0]; c0_[3] = pv3[0];
            c1_[0] = pv0[1]; c1_[1] = pv1[1]; c1_[2] = pv2[1]; c1_[3] = pv3[1];
            c2_[0] = pv0[2]; c2_[1] = pv1[2]; c2_[2] = pv2[2]; c2_[3] = pv3[2];
            c3_[0] = pv0[3]; c3_[1] = pv1[3]; c3_[2] = pv2[3]; c3_[3] = pv3[3];
            *(bf16x4*)(&Vt[(vd4 + 0) * VST + vk4]) = c0_;
            *(bf16x4*)(&Vt[(vd4 + 1) * VST + vk4]) = c1_;
            *(bf16x4*)(&Vt[(vd4 + 2) * VST + vk4]) = c2_;
            *(bf16x4*)(&Vt[(vd4 + 3) * VST + vk4]) = c3_;
        }
        __syncthreads();

        // prefetch next tile
        if (jt + 1 < jt0 + 16) {
            const short* ksrc = kbase + (size_t)((jt + 1) * 64 + krow) * 1024 + kc;
            pk0 = *(const bf16x8*)(ksrc);
            pk1 = *(const bf16x8*)(ksrc + 8);
            const short* vs = vbase + (size_t)((jt + 1) * 64 + vk4) * 1024 + vd4;
            pv0 = *(const bf16x4*)(vs);
            pv1 = *(const bf16x4*)(vs + 1024);
            pv2 = *(const bf16x4*)(vs + 2048);
            pv3 = *(const bf16x4*)(vs + 3072);
        }

        // --- S^T = K Q^T (2 key-groups x 4 k-steps), P = exp2, b64 stores ---
#pragma unroll
        for (int kg = 0; kg < 2; ++kg) {
            f32x16 s;
#pragma unroll
            for (int r = 0; r < 16; ++r) s[r] = 0.f;
#pragma unroll
            for (int st = 0; st < 4; ++st) {
                const bf16x8 kf = *(const bf16x8*)(&Ks[(kg * 32 + l31) * KST + st * 16 + h2 * 8]);
                s = __builtin_amdgcn_mfma_f32_32x32x16_bf16(kf, qr[st], s, 0, 0, 0);
            }
#pragma unroll
            for (int g = 0; g < 4; ++g) {
                const float p0 = __builtin_amdgcn_exp2f(s[4 * g + 0]);
                const float p1 = __builtin_amdgcn_exp2f(s[4 * g + 1]);
                const float p2 = __builtin_amdgcn_exp2f(s[4 * g + 2]);
                const float p3 = __builtin_amdgcn_exp2f(s[4 * g + 3]);
                lsum += (p0 + p1) + (p2 + p3);
                uint2 u;
                u.x = pack2bf(p0, p1);
                u.y = pack2bf(p2, p3);
                *(uint2*)(&pw[l31 * PST + kg * 32 + 8 * g + 4 * h2]) = u;
            }
        }
        __builtin_amdgcn_wave_barrier();

        // --- O += P V (4 k-steps x 2 dim-groups) ---
#pragma unroll
        for (int st = 0; st < 4; ++st) {
            const bf16x8 pf = *(const bf16x8*)(&pw[l31 * PST + st * 16 + h2 * 8]);
#pragma unroll
            for (int dg = 0; dg < 2; ++dg) {
                const bf16x8 vf = *(const bf16x8*)(&Vt[(dg * 32 + l31) * VST + st * 16 + h2 * 8]);
                oacc[dg] = __builtin_amdgcn_mfma_f32_32x32x16_bf16(pf, vf, oacc[dg], 0, 0, 0);
            }
        }
        __builtin_amdgcn_wave_barrier();
    }

    // --- epilogue: combine h2 halves of lsum; store partial l and O ---
    lsum += __shfl_xor(lsum, 32);     // all 64 keys for query = w*32 + l31
    short* nb = numb + (size_t)half * ROWS * 512;
    float* lb = lbuf + (size_t)half * ROWS * 8;
    if (lane < 32)
        lb[(size_t)(b * SEQ + iq0 + w * 32 + l31) * 8 + h] = lsum;
#pragma unroll
    for (int dg = 0; dg < 2; ++dg)
#pragma unroll
        for (int r = 0; r < 16; ++r) {
            const int qrow = w * 32 + (r & 3) + 8 * (r >> 2) + 4 * h2;
            nb[(size_t)(b * SEQ + iq0 + qrow) * 512 + h * 64 + dg * 32 + l31] =
                f2bf(oacc[dg][r]);
        }
}

// ---------------------------------------------------------------------------
extern "C" void kernel_launch(void* const* d_in, const int* in_sizes, int n_in,
                              void* d_out, int out_size, void* d_ws, size_t ws_size,
                              hipStream_t stream) {
    const float* x   = (const float*)d_in[0];  // (4,2048,256)
    const float* ctx = (const float*)d_in[1];  // (4,2048,256)
    const float* Wq  = (const float*)d_in[2];  // (512,256)
    const float* bq  = (const float*)d_in[3];
    const float* Wkv = (const float*)d_in[4];  // (1024,256)
    const float* bkv = (const float*)d_in[5];
    const float* Wo  = (const float*)d_in[6];  // (256,512)
    const float* bo  = (const float*)d_in[7];
    float* out = (float*)d_out;                // (4,2048,256) fp32

    short* q2b  = (short*)d_ws;                         // ROWS*512
    short* kv2b = q2b + (size_t)ROWS * 512;             // ROWS*1024
    short* numb = kv2b + (size_t)ROWS * 1024;           // 2*ROWS*512
    float* lbuf = (float*)(numb + (size_t)2 * ROWS * 512); // 2*ROWS*8

    const float qscale = 0.125f * 1.44269504088896f;   // softmax scale + log2e

    // fused q + kv projection (converts fp32 inputs in-staging)
    proj<<<3072, 256, 0, stream>>>(x, Wq, bq, ctx, Wkv, bkv, q2b, kv2b, qscale);
    // attention, split-K x2, 32x32x16 MFMA, XCD-swizzled 1-D grid (1024 blocks)
    attn_mfma<<<NB * NHEADS * (SEQ / 128) * 2, 256, 0, stream>>>(
        q2b, kv2b, numb, lbuf);
    // out = combine(num1,num2)/(l1+l2) * Wo^T + bo
    gemm64_ocomb<<<dim3(256 / 64, ROWS / 64), 256, 0, stream>>>(
        numb, lbuf, Wo, bo, out);
}

// Round 12
// 161.977 us; speedup vs baseline: 1.1160x; 1.0633x over previous
//
#include <hip/hip_runtime.h>
#include <hip/hip_bf16.h>

#define NB 4
#define SEQ 2048
#define NHEADS 8
#define ROWS (NB * SEQ)

typedef __attribute__((ext_vector_type(8))) short bf16x8;
typedef __attribute__((ext_vector_type(4))) short bf16x4;
typedef __attribute__((ext_vector_type(4))) float f32x4;
typedef __attribute__((ext_vector_type(16))) float f32x16;

__device__ inline short f2bf(float x) {
    union { float f; unsigned u; } v; v.f = x;
    unsigned r = v.u + 0x7FFF + ((v.u >> 16) & 1);
    return (short)(r >> 16);
}

__device__ inline unsigned pack2bf(float a, float b) {
    __hip_bfloat162 h = __float22bfloat162_rn(make_float2(a, b));
    unsigned u; __builtin_memcpy(&u, &h, 4);
    return u;
}

// combine two packed-bf16 pairs from the two K-halves and scale: bf16 out
__device__ inline unsigned comb2(unsigned w1, unsigned w2, float inv) {
    union { unsigned v; float f; } a, b, c, d;
    a.v = w1 << 16;          b.v = w2 << 16;
    c.v = w1 & 0xffff0000u;  d.v = w2 & 0xffff0000u;
    return pack2bf((a.f + b.f) * inv, (c.f + d.f) * inv);
}

// ---------------------------------------------------------------------------
// Fused fp32 -> bf16 cast for all 5 inputs (one launch). Unit = 4 elements.
// x 524288 | ctx 524288 | Wq 32768 | Wkv 65536 | Wo 32768 -> 1179648 units.
// ---------------------------------------------------------------------------
__global__ __launch_bounds__(256) void cvt_all(
    const float* __restrict__ x, const float* __restrict__ ctx,
    const float* __restrict__ wq, const float* __restrict__ wkv,
    const float* __restrict__ wo,
    short* __restrict__ xb, short* __restrict__ cb, short* __restrict__ wqb,
    short* __restrict__ wkvb, short* __restrict__ wob)
{
    const int i = blockIdx.x * 256 + threadIdx.x;
    const float* src; short* dst; int off;
    if (i < 524288)       { src = x;   dst = xb;   off = i; }
    else if (i < 1048576) { src = ctx; dst = cb;   off = i - 524288; }
    else if (i < 1081344) { src = wq;  dst = wqb;  off = i - 1048576; }
    else if (i < 1146880) { src = wkv; dst = wkvb; off = i - 1081344; }
    else                  { src = wo;  dst = wob;  off = i - 1146880; }
    const float4 v = ((const float4*)src)[off];
    uint2 o2;
    o2.x = pack2bf(v.x, v.y);
    o2.y = pack2bf(v.z, v.w);
    *(uint2*)(dst + (size_t)off * 4) = o2;
}

// ---------------------------------------------------------------------------
// Merged q+kv projection, pure bf16, 128x128 tiles, BK=64, K=256.
// Grid 768: bid<512 -> kv tile (col=bid&7, row=bid>>3, Ccols=1024);
//           bid>=512 -> q tile (u=bid-512, col=u&3, row=u>>2, Ccols=512,
//           output pre-scaled by qscale = 0.125*log2e).
// 4 waves in 2x2, each 64x64. XOR-swizzled unpadded LDS; register prefetch.
// launch_bounds(256,3): 3 co-resident blocks/CU overlap barrier drains.
// ---------------------------------------------------------------------------
__global__ __launch_bounds__(256, 3) void proj2(
    const short* __restrict__ xb, const short* __restrict__ wqb,
    const float* __restrict__ bq,
    const short* __restrict__ cb, const short* __restrict__ wkvb,
    const float* __restrict__ bkv,
    short* __restrict__ q2b, short* __restrict__ kv2b, float qscale)
{
    __shared__ short As[128 * 64];
    __shared__ short Ws[128 * 64];
    const int tid = threadIdx.x;
    const int bid = blockIdx.x;
    const int w = tid >> 6, lane = tid & 63, low = lane & 15, quad = lane >> 4;
    const int wm = w >> 1, wn = w & 1;
    const int K = 256;

    const short* A; const short* W; const float* bias;
    short* outp; int Ccols; float scale; int rM0, c0;
    if (bid < 512) {
        A = cb; W = wkvb; bias = bkv; outp = kv2b; Ccols = 1024; scale = 1.0f;
        c0 = (bid & 7) * 128; rM0 = (bid >> 3) * 128;
    } else {
        const int u = bid - 512;
        A = xb; W = wqb; bias = bq; outp = q2b; Ccols = 512; scale = qscale;
        c0 = (u & 3) * 128; rM0 = (u >> 2) * 128;
    }

    const int srow = tid >> 3, sj = tid & 7;

    f32x4 acc[4][4];
#pragma unroll
    for (int mt = 0; mt < 4; ++mt)
#pragma unroll
        for (int nt = 0; nt < 4; ++nt) acc[mt][nt] = (f32x4){0.f, 0.f, 0.f, 0.f};

    bf16x8 pab[4], pwb[4];
#pragma unroll
    for (int c = 0; c < 4; ++c) {
        const int row = c * 32 + srow;
        pab[c] = *(const bf16x8*)(A + (size_t)(rM0 + row) * K + sj * 8);
        pwb[c] = *(const bf16x8*)(W + (size_t)(c0 + row) * K + sj * 8);
    }

    int k0 = 0;
    for (;;) {
        __syncthreads();
#pragma unroll
        for (int c = 0; c < 4; ++c) {
            const int row = c * 32 + srow;
            const int pc = sj ^ (row & 7);
            *(bf16x8*)(&As[row * 64 + pc * 8]) = pab[c];
            *(bf16x8*)(&Ws[row * 64 + pc * 8]) = pwb[c];
        }
        __syncthreads();
        const int kn = k0 + 64;
        if (kn < K) {
#pragma unroll
            for (int c = 0; c < 4; ++c) {
                const int row = c * 32 + srow;
                pab[c] = *(const bf16x8*)(A + (size_t)(rM0 + row) * K + kn + sj * 8);
                pwb[c] = *(const bf16x8*)(W + (size_t)(c0 + row) * K + kn + sj * 8);
            }
        }
#pragma unroll
        for (int kh = 0; kh < 2; ++kh) {
            bf16x8 af[4], bfv[4];
#pragma unroll
            for (int t = 0; t < 4; ++t) {
                const int ra = wm * 64 + t * 16 + low;
                af[t] = *(const bf16x8*)(&As[ra * 64 + ((kh * 4 + quad) ^ (ra & 7)) * 8]);
                const int rb = wn * 64 + t * 16 + low;
                bfv[t] = *(const bf16x8*)(&Ws[rb * 64 + ((kh * 4 + quad) ^ (rb & 7)) * 8]);
            }
#pragma unroll
            for (int mt = 0; mt < 4; ++mt)
#pragma unroll
                for (int nt = 0; nt < 4; ++nt)
                    acc[mt][nt] = __builtin_amdgcn_mfma_f32_16x16x32_bf16(af[mt], bfv[nt], acc[mt][nt], 0, 0, 0);
        }
        k0 = kn;
        if (k0 >= K) break;
    }

#pragma unroll
    for (int nt = 0; nt < 4; ++nt) {
        const int col = c0 + wn * 64 + nt * 16 + low;
        const float bv = bias[col];
#pragma unroll
        for (int mt = 0; mt < 4; ++mt) {
            const size_t rbase = (size_t)(rM0 + wm * 64 + mt * 16 + quad * 4);
#pragma unroll
            for (int r = 0; r < 4; ++r)
                outp[(rbase + r) * Ccols + col] = f2bf((acc[mt][nt][r] + bv) * scale);
        }
    }
}

// ---------------------------------------------------------------------------
// o-GEMM with fused split-K combine, all-bf16 staging (Wo pre-cast):
// A[r][e] = (num1[r][e]+num2[r][e]) / (l1[r][h]+l2[r][h]), h = e/64.
// ---------------------------------------------------------------------------
__global__ __launch_bounds__(256) void gemm64_ocomb(
    const short* __restrict__ num, const float* __restrict__ lbuf,
    const short* __restrict__ W, const float* __restrict__ bias,
    float* __restrict__ out)
{
    const int K = 512, Ccols = 256;
    const size_t NHALF = (size_t)ROWS * 512;
    const int R8 = ROWS * 8;
    __shared__ short As[64 * 64];
    __shared__ short Ws[64 * 64];
    const int tid = threadIdx.x;
    const int w = tid >> 6, lane = tid & 63, low = lane & 15, quad = lane >> 4;
    const int wm = w >> 1, wn = w & 1;
    const int r0 = blockIdx.y * 64, c0 = blockIdx.x * 64;
    const int srow = tid >> 2;
    const int sc = (tid & 3) * 2;

    f32x4 acc[2][2];
#pragma unroll
    for (int mt = 0; mt < 2; ++mt)
#pragma unroll
        for (int nt = 0; nt < 2; ++nt) acc[mt][nt] = (f32x4){0.f, 0.f, 0.f, 0.f};

    uint4 pa1[2], pa2[2];
    float pinv;
    bf16x8 pwb[2];

    auto loadA = [&](int k0) {
        const int hh = k0 >> 6;
        const int row = r0 + srow;
        pinv = lbuf[row * 8 + hh] + lbuf[R8 + row * 8 + hh];
        const short* p1 = num + (size_t)row * 512 + k0 + sc * 8;
        pa1[0] = ((const uint4*)p1)[0];
        pa1[1] = ((const uint4*)p1)[1];
        const short* p2 = p1 + NHALF;
        pa2[0] = ((const uint4*)p2)[0];
        pa2[1] = ((const uint4*)p2)[1];
    };
    auto loadW = [&](int k0) {
        const short* p = W + (size_t)(c0 + srow) * K + k0 + sc * 8;
        pwb[0] = ((const bf16x8*)p)[0];
        pwb[1] = ((const bf16x8*)p)[1];
    };

    loadA(0); loadW(0);

    int k0 = 0;
    for (;;) {
        __syncthreads();
        {
            const float inv = 1.f / pinv;
#pragma unroll
            for (int c = 0; c < 2; ++c) {
                const int pc = (sc + c) ^ (srow & 7);
                union { unsigned u[4]; bf16x8 v; } r;
                r.u[0] = comb2(pa1[c].x, pa2[c].x, inv);
                r.u[1] = comb2(pa1[c].y, pa2[c].y, inv);
                r.u[2] = comb2(pa1[c].z, pa2[c].z, inv);
                r.u[3] = comb2(pa1[c].w, pa2[c].w, inv);
                *(bf16x8*)(&As[srow * 64 + pc * 8]) = r.v;
                *(bf16x8*)(&Ws[srow * 64 + pc * 8]) = pwb[c];
            }
        }
        __syncthreads();
        const int kn = k0 + 64;
        if (kn < K) { loadA(kn); loadW(kn); }
#pragma unroll
        for (int kh = 0; kh < 2; ++kh) {
            bf16x8 af[2], bfv[2];
#pragma unroll
            for (int t = 0; t < 2; ++t) {
                const int ra = wm * 32 + t * 16 + low;
                af[t] = *(const bf16x8*)(&As[ra * 64 + ((kh * 4 + quad) ^ (ra & 7)) * 8]);
                const int rb = wn * 32 + t * 16 + low;
                bfv[t] = *(const bf16x8*)(&Ws[rb * 64 + ((kh * 4 + quad) ^ (rb & 7)) * 8]);
            }
#pragma unroll
            for (int mt = 0; mt < 2; ++mt)
#pragma unroll
                for (int nt = 0; nt < 2; ++nt)
                    acc[mt][nt] = __builtin_amdgcn_mfma_f32_16x16x32_bf16(af[mt], bfv[nt], acc[mt][nt], 0, 0, 0);
        }
        k0 = kn;
        if (k0 >= K) break;
    }

#pragma unroll
    for (int nt = 0; nt < 2; ++nt) {
        const int col = c0 + wn * 32 + nt * 16 + low;
        const float bv = bias[col];
#pragma unroll
        for (int mt = 0; mt < 2; ++mt) {
            const size_t rbase = (size_t)(r0 + wm * 32 + mt * 16 + quad * 4);
#pragma unroll
            for (int r = 0; r < 4; ++r)
                out[(rbase + r) * Ccols + col] = acc[mt][nt][r] + bv;
        }
    }
}

// ---------------------------------------------------------------------------
// MFMA flash attention (32x32x16), R9 structure (unchanged): split-K x2 over
// keys, XCD-swizzled 1-D grid, reads pre-projected/pre-scaled q2.
// Layouts (32x32x16, verified m74/m101):
//   A: A[m = lane&31][k = (lane>>5)*8 + j]
//   B: B[k = (lane>>5)*8 + j][n = lane&31]
//   C: col(n) = lane&31, row(m) = (reg&3) + 8*(reg>>2) + 4*(lane>>5)
// ---------------------------------------------------------------------------
#define KST 72
#define VST 72
#define PST 72

__global__ __launch_bounds__(256) void attn_mfma(
    const short* __restrict__ q2,   // ROWS x 512 bf16 (pre-scaled)
    const short* __restrict__ kv2,  // ROWS x 1024 bf16
    short* __restrict__ numb,       // 2 x ROWS x 512 bf16 (unnormalized O)
    float* __restrict__ lbuf)       // 2 x ROWS x 8 fp32
{
    __shared__ short Ks[64 * KST];
    __shared__ short Vt[64 * VST];
    __shared__ short Ps[4][32 * PST];

    const int tid = threadIdx.x;
    const int w = tid >> 6;
    const int lane = tid & 63;
    const int l31 = lane & 31;
    const int h2 = lane >> 5;

    // XCD swizzle decode
    const int flat = blockIdx.x;
    const int h = flat & 7;
    const int rest = flat >> 3;
    const int half = rest & 1;
    const int rest2 = rest >> 1;
    const int qtile = rest2 & 15;
    const int b = rest2 >> 4;
    const int iq0 = qtile * 128;
    const int jt0 = half * 16;

    // --- Q fragments: B operand, 4 k-steps, registers all kernel ---
    bf16x8 qr[4];
#pragma unroll
    for (int st = 0; st < 4; ++st)
        qr[st] = *(const bf16x8*)(q2 + (size_t)(b * SEQ + iq0 + w * 32 + l31) * 512
                                  + h * 64 + st * 16 + h2 * 8);

    const short* kbase = kv2 + (size_t)(b * SEQ) * 1024 + h * 64;
    const short* vbase = kbase + 512;
    short* pw = &Ps[w][0];

    float lsum = 0.f;                 // partial: query = l31, this lane's keys
    f32x16 oacc[2];                   // [dg]; col = dim, rows = queries
#pragma unroll
    for (int dg = 0; dg < 2; ++dg)
#pragma unroll
        for (int r = 0; r < 16; ++r) oacc[dg][r] = 0.f;

    // staging indices
    const int krow = tid >> 2;          // key row 0..63
    const int kc = (tid & 3) * 16;      // dim chunk (shorts)
    const int vk4 = (tid & 15) * 4;     // key base (V^T)
    const int vd4 = (tid >> 4) * 4;     // dim base 0..60

    // --- prefetch first tile of this half ---
    bf16x8 pk0, pk1;
    bf16x4 pv0, pv1, pv2, pv3;
    {
        const short* ksrc = kbase + (size_t)(jt0 * 64 + krow) * 1024 + kc;
        pk0 = *(const bf16x8*)(ksrc);
        pk1 = *(const bf16x8*)(ksrc + 8);
        const short* vs = vbase + (size_t)(jt0 * 64 + vk4) * 1024 + vd4;
        pv0 = *(const bf16x4*)(vs);
        pv1 = *(const bf16x4*)(vs + 1024);
        pv2 = *(const bf16x4*)(vs + 2048);
        pv3 = *(const bf16x4*)(vs + 3072);
    }

    for (int jt = jt0; jt < jt0 + 16; ++jt) {
        __syncthreads();
        *(bf16x8*)(&Ks[krow * KST + kc]) = pk0;
        *(bf16x8*)(&Ks[krow * KST + kc + 8]) = pk1;
        {
            bf16x4 c0_, c1_, c2_, c3_;
            c0_[0] = pv0[0]; c0_[1] = pv1[0]; c0_[2] = pv2[0]; c0_[3] = pv3[0];
            c1_[0] = pv0[1]; c1_[1] = pv1[1]; c1_[2] = pv2[1]; c1_[3] = pv3[1];
            c2_[0] = pv0[2]; c2_[1] = pv1[2]; c2_[2] = pv2[2]; c2_[3] = pv3[2];
            c3_[0] = pv0[3]; c3_[1] = pv1[3]; c3_[2] = pv2[3]; c3_[3] = pv3[3];
            *(bf16x4*)(&Vt[(vd4 + 0) * VST + vk4]) = c0_;
            *(bf16x4*)(&Vt[(vd4 + 1) * VST + vk4]) = c1_;
            *(bf16x4*)(&Vt[(vd4 + 2) * VST + vk4]) = c2_;
            *(bf16x4*)(&Vt[(vd4 + 3) * VST + vk4]) = c3_;
        }
        __syncthreads();

        // prefetch next tile
        if (jt + 1 < jt0 + 16) {
            const short* ksrc = kbase + (size_t)((jt + 1) * 64 + krow) * 1024 + kc;
            pk0 = *(const bf16x8*)(ksrc);
            pk1 = *(const bf16x8*)(ksrc + 8);
            const short* vs = vbase + (size_t)((jt + 1) * 64 + vk4) * 1024 + vd4;
            pv0 = *(const bf16x4*)(vs);
            pv1 = *(const bf16x4*)(vs + 1024);
            pv2 = *(const bf16x4*)(vs + 2048);
            pv3 = *(const bf16x4*)(vs + 3072);
        }

        // --- S^T = K Q^T (2 key-groups x 4 k-steps), P = exp2, b64 stores ---
#pragma unroll
        for (int kg = 0; kg < 2; ++kg) {
            f32x16 s;
#pragma unroll
            for (int r = 0; r < 16; ++r) s[r] = 0.f;
#pragma unroll
            for (int st = 0; st < 4; ++st) {
                const bf16x8 kf = *(const bf16x8*)(&Ks[(kg * 32 + l31) * KST + st * 16 + h2 * 8]);
                s = __builtin_amdgcn_mfma_f32_32x32x16_bf16(kf, qr[st], s, 0, 0, 0);
            }
#pragma unroll
            for (int g = 0; g < 4; ++g) {
                const float p0 = __builtin_amdgcn_exp2f(s[4 * g + 0]);
                const float p1 = __builtin_amdgcn_exp2f(s[4 * g + 1]);
                const float p2 = __builtin_amdgcn_exp2f(s[4 * g + 2]);
                const float p3 = __builtin_amdgcn_exp2f(s[4 * g + 3]);
                lsum += (p0 + p1) + (p2 + p3);
                uint2 u;
                u.x = pack2bf(p0, p1);
                u.y = pack2bf(p2, p3);
                *(uint2*)(&pw[l31 * PST + kg * 32 + 8 * g + 4 * h2]) = u;
            }
        }
        __builtin_amdgcn_wave_barrier();

        // --- O += P V (4 k-steps x 2 dim-groups) ---
#pragma unroll
        for (int st = 0; st < 4; ++st) {
            const bf16x8 pf = *(const bf16x8*)(&pw[l31 * PST + st * 16 + h2 * 8]);
#pragma unroll
            for (int dg = 0; dg < 2; ++dg) {
                const bf16x8 vf = *(const bf16x8*)(&Vt[(dg * 32 + l31) * VST + st * 16 + h2 * 8]);
                oacc[dg] = __builtin_amdgcn_mfma_f32_32x32x16_bf16(pf, vf, oacc[dg], 0, 0, 0);
            }
        }
        __builtin_amdgcn_wave_barrier();
    }

    // --- epilogue: combine h2 halves of lsum; store partial l and O ---
    lsum += __shfl_xor(lsum, 32);     // all 64 keys for query = w*32 + l31
    short* nb = numb + (size_t)half * ROWS * 512;
    float* lb = lbuf + (size_t)half * ROWS * 8;
    if (lane < 32)
        lb[(size_t)(b * SEQ + iq0 + w * 32 + l31) * 8 + h] = lsum;
#pragma unroll
    for (int dg = 0; dg < 2; ++dg)
#pragma unroll
        for (int r = 0; r < 16; ++r) {
            const int qrow = w * 32 + (r & 3) + 8 * (r >> 2) + 4 * h2;
            nb[(size_t)(b * SEQ + iq0 + qrow) * 512 + h * 64 + dg * 32 + l31] =
                f2bf(oacc[dg][r]);
        }
}

// ---------------------------------------------------------------------------
extern "C" void kernel_launch(void* const* d_in, const int* in_sizes, int n_in,
                              void* d_out, int out_size, void* d_ws, size_t ws_size,
                              hipStream_t stream) {
    const float* x   = (const float*)d_in[0];  // (4,2048,256)
    const float* ctx = (const float*)d_in[1];  // (4,2048,256)
    const float* Wq  = (const float*)d_in[2];  // (512,256)
    const float* bq  = (const float*)d_in[3];
    const float* Wkv = (const float*)d_in[4];  // (1024,256)
    const float* bkv = (const float*)d_in[5];
    const float* Wo  = (const float*)d_in[6];  // (256,512)
    const float* bo  = (const float*)d_in[7];
    float* out = (float*)d_out;                // (4,2048,256) fp32

    short* xb   = (short*)d_ws;                         // ROWS*256
    short* cb   = xb + (size_t)ROWS * 256;              // ROWS*256
    short* wqb  = cb + (size_t)ROWS * 256;              // 131072
    short* wkvb = wqb + 131072;                         // 262144
    short* wob  = wkvb + 262144;                        // 131072
    short* q2b  = wob + 131072;                         // ROWS*512
    short* kv2b = q2b + (size_t)ROWS * 512;             // ROWS*1024
    short* numb = kv2b + (size_t)ROWS * 1024;           // 2*ROWS*512
    float* lbuf = (float*)(numb + (size_t)2 * ROWS * 512); // 2*ROWS*8

    const float qscale = 0.125f * 1.44269504088896f;   // softmax scale + log2e

    cvt_all<<<4608, 256, 0, stream>>>(x, ctx, Wq, Wkv, Wo,
                                      xb, cb, wqb, wkvb, wob);
    // merged q+kv projection, 128x128 tiles, pure bf16 (768 blocks = 3/CU)
    proj2<<<768, 256, 0, stream>>>(xb, wqb, bq, cb, wkvb, bkv,
                                   q2b, kv2b, qscale);
    // attention, split-K x2, 32x32x16 MFMA, XCD-swizzled 1-D grid (1024 blocks)
    attn_mfma<<<NB * NHEADS * (SEQ / 128) * 2, 256, 0, stream>>>(
        q2b, kv2b, numb, lbuf);
    // out = combine(num1,num2)/(l1+l2) * Wo^T + bo (bf16 Wo)
    gemm64_ocomb<<<dim3(256 / 64, ROWS / 64), 256, 0, stream>>>(
        numb, lbuf, wob, bo, out);
}